// Round 11
// baseline (490.633 us; speedup 1.0000x reference)
//
#include <hip/hip_runtime.h>

typedef __bf16 bf16_t;
typedef __bf16 bf16x8 __attribute__((ext_vector_type(8)));
typedef __bf16 bf16x4 __attribute__((ext_vector_type(4)));
typedef float  f32x4  __attribute__((ext_vector_type(4)));

#define HW_ 65536
#define C_  128

// XOR swizzle: spread 16B slots (byte bits [6:4]) by row index. Applied
// identically on LDS write and read; bijective within each 128B span.
__device__ __forceinline__ int swz(int r) { return ((r ^ (r >> 3)) & 7) << 4; }

#define LGKM0() asm volatile("s_waitcnt lgkmcnt(0)" ::: "memory")
__device__ __forceinline__ void BAR() {
  asm volatile("" ::: "memory");
  __builtin_amdgcn_s_barrier();
  asm volatile("" ::: "memory");
}

// =====================================================================
// Phase 1 (R1 verbatim, measured 154us): map = PReLU(W*x + b).
// Per-b GEMM M=128,K=128,N=128/WG.
// LDS: Xs at 0 (32KB): x-tile transposed bf16; Ws at 32768 (32KB).
// HBLK: mH w-blocked [c][w>>6][h][w&63] for attn PV staging reads.
// =====================================================================
template<bool HBLK>
__device__ __forceinline__ void conv_one(char* lds, const float* __restrict__ Wsrc,
                                         const float* __restrict__ bias, float alpha,
                                         bf16_t* __restrict__ dst, size_t pb,
                                         int wv, int lr, int lq, int t, int s0)
{
  __syncthreads();
  #pragma unroll
  for (int rep = 0; rep < 16; ++rep) {
    int q = rep * 256 + t;
    int o = q >> 5, c0 = (q & 31) * 4;
    f32x4 w4 = *(const f32x4*)(Wsrc + o * C_ + c0);
    bf16x4 v;
    v[0] = (bf16_t)w4[0]; v[1] = (bf16_t)w4[1]; v[2] = (bf16_t)w4[2]; v[3] = (bf16_t)w4[3];
    *(bf16x4*)(lds + 32768 + ((o * 256 + c0 * 2) ^ swz(o))) = v;
  }
  __syncthreads();

  const f32x4 fz = {0.f, 0.f, 0.f, 0.f};
  f32x4 acc[2][8];
  #pragma unroll
  for (int mf = 0; mf < 2; ++mf)
    #pragma unroll
    for (int nf = 0; nf < 8; ++nf)
      acc[mf][nf] = fz;

  #pragma unroll
  for (int ks = 0; ks < 4; ++ks) {
    int kb = ks * 32 + lq * 8;
    bf16x8 a[2], bb[8];
    #pragma unroll
    for (int mf = 0; mf < 2; ++mf) {
      int m = wv * 32 + mf * 16 + lr;
      a[mf] = *(const bf16x8*)(lds + 32768 + ((m * 256 + kb * 2) ^ swz(m)));
    }
    #pragma unroll
    for (int nf = 0; nf < 8; ++nf) {
      int n = nf * 16 + lr;
      bb[nf] = *(const bf16x8*)(lds + ((n * 256 + kb * 2) ^ swz(n)));
    }
    #pragma unroll
    for (int mf = 0; mf < 2; ++mf)
      #pragma unroll
      for (int nf = 0; nf < 8; ++nf)
        acc[mf][nf] = __builtin_amdgcn_mfma_f32_16x16x32_bf16(a[mf], bb[nf], acc[mf][nf], 0, 0, 0);
  }

  #pragma unroll
  for (int mf = 0; mf < 2; ++mf) {
    #pragma unroll
    for (int i = 0; i < 4; ++i) {
      int o = wv * 32 + mf * 16 + lq * 4 + i;
      float bo = bias[o];
      #pragma unroll
      for (int nf = 0; nf < 8; ++nf) {
        int s = s0 + nf * 16 + lr;
        float v = acc[mf][nf][i] + bo;
        v = (v >= 0.f) ? v : alpha * v;
        size_t off;
        if (HBLK) {                       // w-blocked layout [c][w>>6][h][w&63]
          int h = s >> 8, w = s & 255;
          off = pb + (size_t)o * HW_ + (size_t)(w >> 6) * 16384 + h * 64 + (w & 63);
        } else {
          off = pb + (size_t)o * HW_ + s; // natural [c][h][w]
        }
        dst[off] = (bf16_t)v;
      }
    }
  }
}

__global__ __launch_bounds__(256, 2) void conv_kernel(
    const float* __restrict__ x,
    const float* __restrict__ Wf, const float* __restrict__ bfp, const float* __restrict__ afp,
    const float* __restrict__ Wg, const float* __restrict__ bgp, const float* __restrict__ agp,
    const float* __restrict__ Wh, const float* __restrict__ bhp, const float* __restrict__ ahp,
    bf16_t* __restrict__ mF, bf16_t* __restrict__ mG, bf16_t* __restrict__ mH, int b0)
{
  __shared__ __align__(16) char lds[65536];
  const int t = threadIdx.x;
  const int bloc = blockIdx.y;
  const int s0 = blockIdx.x * 128;
  const size_t xbase = ((size_t)(b0 + bloc) * C_) * HW_ + s0;

  #pragma unroll
  for (int rep = 0; rep < 4; ++rep) {
    int q = rep * 256 + t;
    int c0 = (q >> 5) * 4, sl0 = (q & 31) * 4;
    f32x4 r[4];
    #pragma unroll
    for (int i = 0; i < 4; ++i)
      r[i] = *(const f32x4*)(x + xbase + (size_t)(c0 + i) * HW_ + sl0);
    #pragma unroll
    for (int js = 0; js < 4; ++js) {
      int s = sl0 + js;
      bf16x4 v;
      v[0] = (bf16_t)r[0][js]; v[1] = (bf16_t)r[1][js];
      v[2] = (bf16_t)r[2][js]; v[3] = (bf16_t)r[3][js];
      *(bf16x4*)(lds + ((s * 256 + c0 * 2) ^ swz(s))) = v;
    }
  }

  const int wv = t >> 6, lane = t & 63, lr = lane & 15, lq = lane >> 4;
  const size_t pb = (size_t)bloc * C_ * HW_;
  conv_one<false>(lds, Wf, bfp, afp[0], mF, pb, wv, lr, lq, t, s0);
  conv_one<false>(lds, Wg, bgp, agp[0], mG, pb, wv, lr, lq, t, s0);
  conv_one<true >(lds, Wh, bhp, ahp[0], mH, pb, wv, lr, lq, t, s0);
}

// =====================================================================
// Phase 2 (R10 + S depth-2 prefetch + x-preload into PV acc):
// 512 thr / 8 waves.  LDS is the occupancy binder (1 WG/CU) so VGPR up to
// 256 is free — spend it on pipeline depth.
// LDS map (155648 B):
//   [0,32768)        Ft chunk  [w=256][h=64] bf16 swizzled   (S phase)
//   [32768,65536)    Gt chunk  [v=256][h=64] bf16 swizzled   (S phase)
//   [0,131072)       PT        [v=256][w=256] bf16 swizzled  (PV phase)
//   [131072,151552)  Hs chunk  [h=256][w=32] bf16, 80B row pitch
//   [151552,153600)  smax [2][256] f32 ; [153600,155648) ssum [2][256] f32
// S delta: 2-deep prefetch (chunks 0,1 issued upfront; k+2 after k's write).
// PV delta: residual x loaded in 16-value batches during PV and VALU-added
// into the MFMA accumulator (C-in linearity) -> epilogue is pure stores.
// =====================================================================
#define GT_OFF  32768
#define HS_OFF  131072
#define SMAX_OFF 151552
#define SSUM_OFF 153600
#define SMEM_BYTES 155648

__global__ __launch_bounds__(512, 2) void attn_kernel(
    const bf16_t* __restrict__ mF, const bf16_t* __restrict__ mG, const bf16_t* __restrict__ mH,
    const float* __restrict__ x, float* __restrict__ out, int b0)
{
  extern __shared__ __align__(16) char smem[];
  const int t = threadIdx.x;
  const int c = blockIdx.x, bloc = blockIdx.y;
  const int wv = t >> 6, lane = t & 63, lr = lane & 15, lq = lane >> 4;
  const int wr = wv >> 1, wc = wv & 1;
  const size_t plane  = ((size_t)bloc * C_ + c) * HW_;            // maps (per-pass)
  const size_t gplane = (((size_t)(b0 + bloc)) * C_ + c) * HW_;   // x / out (global)

  const f32x4 fz = {0.f, 0.f, 0.f, 0.f};
  f32x4 acc[4][8];
  #pragma unroll
  for (int mf = 0; mf < 4; ++mf)
    #pragma unroll
    for (int nf = 0; nf < 8; ++nf)
      acc[mf][nf] = fz;

  const int hq = t >> 5, wb8 = t & 31;   // staging decomposition

  // ---- S = F^T G, 4 chunks of 64 h; 2-deep global prefetch ----
  bf16x8 pfF[2][4], pfG[2][4];
  #pragma unroll
  for (int p = 0; p < 2; ++p)
    #pragma unroll
    for (int i = 0; i < 4; ++i) {
      pfF[p][i] = *(const bf16x8*)(mF + plane + (size_t)(p * 64 + hq * 4 + i) * 256 + wb8 * 8);
      pfG[p][i] = *(const bf16x8*)(mG + plane + (size_t)(p * 64 + hq * 4 + i) * 256 + wb8 * 8);
    }

  #pragma unroll
  for (int ci = 0; ci < 4; ++ci) {
    const int buf = ci & 1;
    BAR();                             // prev chunk's LDS reads done; Ft/Gt writable
    #pragma unroll
    for (int j = 0; j < 8; ++j) {      // transpose-write (waits vmcnt on pf[buf] only)
      int w = wb8 * 8 + j;
      bf16x4 v; v[0] = pfF[buf][0][j]; v[1] = pfF[buf][1][j];
      v[2] = pfF[buf][2][j]; v[3] = pfF[buf][3][j];
      *(bf16x4*)(smem + ((w * 128 + hq * 8) ^ swz(w))) = v;
      bf16x4 g; g[0] = pfG[buf][0][j]; g[1] = pfG[buf][1][j];
      g[2] = pfG[buf][2][j]; g[3] = pfG[buf][3][j];
      *(bf16x4*)(smem + GT_OFF + ((w * 128 + hq * 8) ^ swz(w))) = g;
    }
    if (ci < 2) {                      // issue chunk ci+2 into just-freed regs
      #pragma unroll
      for (int i = 0; i < 4; ++i) {
        pfF[buf][i] = *(const bf16x8*)(mF + plane + (size_t)((ci + 2) * 64 + hq * 4 + i) * 256 + wb8 * 8);
        pfG[buf][i] = *(const bf16x8*)(mG + plane + (size_t)((ci + 2) * 64 + hq * 4 + i) * 256 + wb8 * 8);
      }
    }
    LGKM0(); BAR();                    // LDS writes visible; vmcnt NOT drained
    #pragma unroll
    for (int k0 = 0; k0 < 64; k0 += 32) {
      int kb = k0 + lq * 8;
      bf16x8 a[4], bb[8];
      #pragma unroll
      for (int mf = 0; mf < 4; ++mf) {
        int m = wr * 64 + mf * 16 + lr;
        a[mf] = *(const bf16x8*)(smem + ((m * 128 + kb * 2) ^ swz(m)));
      }
      #pragma unroll
      for (int nf = 0; nf < 8; ++nf) {
        int n = wc * 128 + nf * 16 + lr;
        bb[nf] = *(const bf16x8*)(smem + GT_OFF + ((n * 128 + kb * 2) ^ swz(n)));
      }
      #pragma unroll
      for (int mf = 0; mf < 4; ++mf)
        #pragma unroll
        for (int nf = 0; nf < 8; ++nf)
          acc[mf][nf] = __builtin_amdgcn_mfma_f32_16x16x32_bf16(a[mf], bb[nf], acc[mf][nf], 0, 0, 0);
    }
  }

  // ---- softmax over v (rows w) (R1 verbatim) ----
  float* smax = (float*)(smem + SMAX_OFF);
  float* ssum = (float*)(smem + SSUM_OFF);
  float rowm[4][4];
  #pragma unroll
  for (int mf = 0; mf < 4; ++mf)
    #pragma unroll
    for (int i = 0; i < 4; ++i) {
      float m = acc[mf][0][i];
      #pragma unroll
      for (int nf = 1; nf < 8; ++nf) m = fmaxf(m, acc[mf][nf][i]);
      #pragma unroll
      for (int d = 1; d < 16; d <<= 1) m = fmaxf(m, __shfl_xor(m, d));
      rowm[mf][i] = m;
    }
  if (lr == 0) {
    #pragma unroll
    for (int mf = 0; mf < 4; ++mf)
      #pragma unroll
      for (int i = 0; i < 4; ++i)
        smax[wc * 256 + wr * 64 + mf * 16 + lq * 4 + i] = rowm[mf][i];
  }
  __syncthreads();
  float m2[4][4], rs[4][4];
  #pragma unroll
  for (int mf = 0; mf < 4; ++mf)
    #pragma unroll
    for (int i = 0; i < 4; ++i) {
      int w = wr * 64 + mf * 16 + lq * 4 + i;
      m2[mf][i] = fmaxf(smax[w], smax[256 + w]);
      rs[mf][i] = 0.f;
    }
  #pragma unroll
  for (int mf = 0; mf < 4; ++mf)
    #pragma unroll
    for (int nf = 0; nf < 8; ++nf)
      #pragma unroll
      for (int i = 0; i < 4; ++i) {
        float e = __expf(acc[mf][nf][i] - m2[mf][i]);
        acc[mf][nf][i] = e;
        rs[mf][i] += e;
      }
  #pragma unroll
  for (int mf = 0; mf < 4; ++mf)
    #pragma unroll
    for (int i = 0; i < 4; ++i) {
      float s = rs[mf][i];
      #pragma unroll
      for (int d = 1; d < 16; d <<= 1) s += __shfl_xor(s, d);
      rs[mf][i] = s;
    }
  if (lr == 0) {
    #pragma unroll
    for (int mf = 0; mf < 4; ++mf)
      #pragma unroll
      for (int i = 0; i < 4; ++i)
        ssum[wc * 256 + wr * 64 + mf * 16 + lq * 4 + i] = rs[mf][i];
  }
  __syncthreads();
  // P = e/sum -> bf16 -> PT[v][w]  (overwrites Ft/Gt region; ordered by barriers)
  #pragma unroll
  for (int mf = 0; mf < 4; ++mf)
    #pragma unroll
    for (int i = 0; i < 4; ++i) {
      int w = wr * 64 + mf * 16 + lq * 4 + i;
      float rinv = 1.f / (ssum[w] + ssum[256 + w]);
      #pragma unroll
      for (int nf = 0; nf < 8; ++nf) {
        int v_ = wc * 128 + nf * 16 + lr;
        *(bf16_t*)(smem + ((v_ * 512 + w * 2) ^ swz(v_))) = (bf16_t)(acc[mf][nf][i] * rinv);
      }
    }

  // ---- out = H*P + x: 8 w-chunks; H 1-ahead; x batches overlap PV ----
  #pragma unroll
  for (int mf = 0; mf < 4; ++mf)
    #pragma unroll
    for (int nf = 0; nf < 8; ++nf)
      acc[mf][nf] = fz;

  // issue chunk-0 H loads early (latency hides under P-write + first barrier)
  bf16x8 hreg[2];
  {
    #pragma unroll
    for (int rep = 0; rep < 2; ++rep) {
      int u = rep * 512 + t;
      int h = u >> 2, wl0 = (u & 3) * 8;
      hreg[rep] = *(const bf16x8*)(mH + plane + h * 64 + wl0);
    }
  }
  // issue x batch 0 (tile mf=0, nf 0..3) AFTER H0 so H0's wait leaves x in flight
  float xv[16];
  #pragma unroll
  for (int n0 = 0; n0 < 4; ++n0)
    #pragma unroll
    for (int i = 0; i < 4; ++i)
      xv[n0 * 4 + i] = x[gplane + (size_t)(wr * 64 + lq * 4 + i) * 256
                         + wc * 128 + n0 * 16 + lr];

  #pragma unroll
  for (int wk = 0; wk < 8; ++wk) {
    LGKM0(); BAR();                    // P-write / prev MFMA reads done; Hs writable
    {
      #pragma unroll
      for (int rep = 0; rep < 2; ++rep) {
        int u = rep * 512 + t;
        int h = u >> 2, wl0 = (u & 3) * 8;
        *(bf16x8*)(smem + HS_OFF + h * 80 + wl0 * 2) = hreg[rep];  // waits vmcnt on hreg
      }
    }
    if (wk < 7) {                      // issue next H chunk; stays in flight across BAR
      const size_t hbase = plane + (size_t)((wk + 1) >> 1) * 16384 + (size_t)((wk + 1) & 1) * 32;
      #pragma unroll
      for (int rep = 0; rep < 2; ++rep) {
        int u = rep * 512 + t;
        int h = u >> 2, wl0 = (u & 3) * 8;
        hreg[rep] = *(const bf16x8*)(mH + hbase + h * 64 + wl0);
      }
    }
    LGKM0(); BAR();                    // Hs writes visible; vmcnt NOT drained
    const int kb = lq * 8;
    bf16x8 a[4], bb[8];
    #pragma unroll
    for (int mf = 0; mf < 4; ++mf) {
      int m = wr * 64 + mf * 16 + lr;
      a[mf] = *(const bf16x8*)(smem + HS_OFF + m * 80 + kb * 2);
    }
    #pragma unroll
    for (int nf = 0; nf < 8; ++nf) {
      int n = wc * 128 + nf * 16 + lr;
      int kg = wk * 32 + kb;
      bb[nf] = *(const bf16x8*)(smem + ((n * 512 + kg * 2) ^ swz(n)));
    }
    #pragma unroll
    for (int mf = 0; mf < 4; ++mf)
      #pragma unroll
      for (int nf = 0; nf < 8; ++nf)
        acc[mf][nf] = __builtin_amdgcn_mfma_f32_16x16x32_bf16(a[mf], bb[nf], acc[mf][nf], 0, 0, 0);

    // fold x batch wk into acc (C-in linearity), then issue batch wk+1
    {
      const int mfb = wk >> 1, nhb = wk & 1;
      #pragma unroll
      for (int n0 = 0; n0 < 4; ++n0)
        #pragma unroll
        for (int i = 0; i < 4; ++i)
          acc[mfb][nhb * 4 + n0][i] += xv[n0 * 4 + i];   // waits vmcnt on xv only
      if (wk < 7) {
        const int mfn = (wk + 1) >> 1, nhn = (wk + 1) & 1;
        #pragma unroll
        for (int n0 = 0; n0 < 4; ++n0)
          #pragma unroll
          for (int i = 0; i < 4; ++i)
            xv[n0 * 4 + i] = x[gplane + (size_t)(wr * 64 + mfn * 16 + lq * 4 + i) * 256
                               + wc * 128 + (nhn * 4 + n0) * 16 + lr];
      }
    }
  }

  // ---- epilogue: pure stores (x already folded in) ----
  #pragma unroll
  for (int mf = 0; mf < 4; ++mf)
    #pragma unroll
    for (int i = 0; i < 4; ++i) {
      int h = wr * 64 + mf * 16 + lq * 4 + i;
      #pragma unroll
      for (int nf = 0; nf < 8; ++nf) {
        int v_ = wc * 128 + nf * 16 + lr;
        out[gplane + (size_t)h * 256 + v_] = acc[mf][nf][i];
      }
    }
}

// =====================================================================
extern "C" void kernel_launch(void* const* d_in, const int* in_sizes, int n_in,
                              void* d_out, int out_size, void* d_ws, size_t ws_size,
                              hipStream_t stream)
{
  (void)in_sizes; (void)n_in; (void)out_size;
  const float* x   = (const float*)d_in[0];
  const float* Wf  = (const float*)d_in[1];
  const float* bfp = (const float*)d_in[2];
  const float* afp = (const float*)d_in[3];
  const float* Wg  = (const float*)d_in[4];
  const float* bgp = (const float*)d_in[5];
  const float* agp = (const float*)d_in[6];
  const float* Wh  = (const float*)d_in[7];
  const float* bhp = (const float*)d_in[8];
  const float* ahp = (const float*)d_in[9];
  float* out = (float*)d_out;

  const size_t per_map_b = (size_t)C_ * HW_ * sizeof(bf16_t);  // 16 MiB per map per batch
  int nb = 1;
  if      (ws_size >= 3 * 8 * per_map_b) nb = 8;
  else if (ws_size >= 3 * 4 * per_map_b) nb = 4;
  else if (ws_size >= 3 * 2 * per_map_b) nb = 2;

  hipFuncSetAttribute(reinterpret_cast<const void*>(attn_kernel),
                      hipFuncAttributeMaxDynamicSharedMemorySize, SMEM_BYTES);

  bf16_t* mF = (bf16_t*)d_ws;
  bf16_t* mG = mF + (size_t)nb * C_ * HW_;
  bf16_t* mH = mG + (size_t)nb * C_ * HW_;

  for (int b0 = 0; b0 < 8; b0 += nb) {
    conv_kernel<<<dim3(512, nb), 256, 0, stream>>>(x, Wf, bfp, afp, Wg, bgp, agp,
                                                   Wh, bhp, ahp, mF, mG, mH, b0);
    attn_kernel<<<dim3(C_, nb), 512, SMEM_BYTES, stream>>>(mF, mG, mH, x, out, b0);
  }
}

// Round 12
// 489.866 us; speedup vs baseline: 1.0016x; 1.0016x over previous
//
#include <hip/hip_runtime.h>

typedef __bf16 bf16_t;
typedef __bf16 bf16x8 __attribute__((ext_vector_type(8)));
typedef __bf16 bf16x4 __attribute__((ext_vector_type(4)));
typedef float  f32x4  __attribute__((ext_vector_type(4)));

#define HW_ 65536
#define C_  128

// XOR swizzle: spread 16B slots (byte bits [6:4]) by row index. Applied
// identically on LDS write and read; bijective within each 128B span.
__device__ __forceinline__ int swz(int r) { return ((r ^ (r >> 3)) & 7) << 4; }

#define LGKM0() asm volatile("s_waitcnt lgkmcnt(0)" ::: "memory")
__device__ __forceinline__ void BAR() {
  asm volatile("" ::: "memory");
  __builtin_amdgcn_s_barrier();
  asm volatile("" ::: "memory");
}

// =====================================================================
// Phase 1 (R1 verbatim, measured 154us): map = PReLU(W*x + b).
// Per-b GEMM M=128,K=128,N=128/WG.
// LDS: Xs at 0 (32KB): x-tile transposed bf16; Ws at 32768 (32KB).
// HBLK: mH w-blocked [c][w>>6][h][w&63] for attn PV staging reads.
// =====================================================================
template<bool HBLK>
__device__ __forceinline__ void conv_one(char* lds, const float* __restrict__ Wsrc,
                                         const float* __restrict__ bias, float alpha,
                                         bf16_t* __restrict__ dst, size_t pb,
                                         int wv, int lr, int lq, int t, int s0)
{
  __syncthreads();
  #pragma unroll
  for (int rep = 0; rep < 16; ++rep) {
    int q = rep * 256 + t;
    int o = q >> 5, c0 = (q & 31) * 4;
    f32x4 w4 = *(const f32x4*)(Wsrc + o * C_ + c0);
    bf16x4 v;
    v[0] = (bf16_t)w4[0]; v[1] = (bf16_t)w4[1]; v[2] = (bf16_t)w4[2]; v[3] = (bf16_t)w4[3];
    *(bf16x4*)(lds + 32768 + ((o * 256 + c0 * 2) ^ swz(o))) = v;
  }
  __syncthreads();

  const f32x4 fz = {0.f, 0.f, 0.f, 0.f};
  f32x4 acc[2][8];
  #pragma unroll
  for (int mf = 0; mf < 2; ++mf)
    #pragma unroll
    for (int nf = 0; nf < 8; ++nf)
      acc[mf][nf] = fz;

  #pragma unroll
  for (int ks = 0; ks < 4; ++ks) {
    int kb = ks * 32 + lq * 8;
    bf16x8 a[2], bb[8];
    #pragma unroll
    for (int mf = 0; mf < 2; ++mf) {
      int m = wv * 32 + mf * 16 + lr;
      a[mf] = *(const bf16x8*)(lds + 32768 + ((m * 256 + kb * 2) ^ swz(m)));
    }
    #pragma unroll
    for (int nf = 0; nf < 8; ++nf) {
      int n = nf * 16 + lr;
      bb[nf] = *(const bf16x8*)(lds + ((n * 256 + kb * 2) ^ swz(n)));
    }
    #pragma unroll
    for (int mf = 0; mf < 2; ++mf)
      #pragma unroll
      for (int nf = 0; nf < 8; ++nf)
        acc[mf][nf] = __builtin_amdgcn_mfma_f32_16x16x32_bf16(a[mf], bb[nf], acc[mf][nf], 0, 0, 0);
  }

  #pragma unroll
  for (int mf = 0; mf < 2; ++mf) {
    #pragma unroll
    for (int i = 0; i < 4; ++i) {
      int o = wv * 32 + mf * 16 + lq * 4 + i;
      float bo = bias[o];
      #pragma unroll
      for (int nf = 0; nf < 8; ++nf) {
        int s = s0 + nf * 16 + lr;
        float v = acc[mf][nf][i] + bo;
        v = (v >= 0.f) ? v : alpha * v;
        size_t off;
        if (HBLK) {                       // w-blocked layout [c][w>>6][h][w&63]
          int h = s >> 8, w = s & 255;
          off = pb + (size_t)o * HW_ + (size_t)(w >> 6) * 16384 + h * 64 + (w & 63);
        } else {
          off = pb + (size_t)o * HW_ + s; // natural [c][h][w]
        }
        dst[off] = (bf16_t)v;
      }
    }
  }
}

__global__ __launch_bounds__(256, 2) void conv_kernel(
    const float* __restrict__ x,
    const float* __restrict__ Wf, const float* __restrict__ bfp, const float* __restrict__ afp,
    const float* __restrict__ Wg, const float* __restrict__ bgp, const float* __restrict__ agp,
    const float* __restrict__ Wh, const float* __restrict__ bhp, const float* __restrict__ ahp,
    bf16_t* __restrict__ mF, bf16_t* __restrict__ mG, bf16_t* __restrict__ mH, int b0)
{
  __shared__ __align__(16) char lds[65536];
  const int t = threadIdx.x;
  const int bloc = blockIdx.y;
  const int s0 = blockIdx.x * 128;
  const size_t xbase = ((size_t)(b0 + bloc) * C_) * HW_ + s0;

  #pragma unroll
  for (int rep = 0; rep < 4; ++rep) {
    int q = rep * 256 + t;
    int c0 = (q >> 5) * 4, sl0 = (q & 31) * 4;
    f32x4 r[4];
    #pragma unroll
    for (int i = 0; i < 4; ++i)
      r[i] = *(const f32x4*)(x + xbase + (size_t)(c0 + i) * HW_ + sl0);
    #pragma unroll
    for (int js = 0; js < 4; ++js) {
      int s = sl0 + js;
      bf16x4 v;
      v[0] = (bf16_t)r[0][js]; v[1] = (bf16_t)r[1][js];
      v[2] = (bf16_t)r[2][js]; v[3] = (bf16_t)r[3][js];
      *(bf16x4*)(lds + ((s * 256 + c0 * 2) ^ swz(s))) = v;
    }
  }

  const int wv = t >> 6, lane = t & 63, lr = lane & 15, lq = lane >> 4;
  const size_t pb = (size_t)bloc * C_ * HW_;
  conv_one<false>(lds, Wf, bfp, afp[0], mF, pb, wv, lr, lq, t, s0);
  conv_one<false>(lds, Wg, bgp, agp[0], mG, pb, wv, lr, lq, t, s0);
  conv_one<true >(lds, Wh, bhp, ahp[0], mH, pb, wv, lr, lq, t, s0);
}

// =====================================================================
// Phase 2 (R11 pipelines + UNCAPPED VGPR): 512 thr / 8 waves.
// LDS (152 KB) pins occupancy at 1 WG/CU = 2 waves/SIMD, where the HW
// VGPR budget is 256/wave.  launch_bounds(512,1) (was (512,2)) lifts the
// 128-VGPR compiler cap that was spilling R11's pipeline state to scratch
// (+167 MB FETCH / +344 MB WRITE of pure spill traffic).
// LDS map (155648 B):
//   [0,32768)        Ft chunk  [w=256][h=64] bf16 swizzled   (S phase)
//   [32768,65536)    Gt chunk  [v=256][h=64] bf16 swizzled   (S phase)
//   [0,131072)       PT        [v=256][w=256] bf16 swizzled  (PV phase)
//   [131072,151552)  Hs chunk  [h=256][w=32] bf16, 80B row pitch
//   [151552,153600)  smax [2][256] f32 ; [153600,155648) ssum [2][256] f32
// S: 2-deep global prefetch (chunks 0,1 upfront; k+2 after k's write).
// PV: H 1-ahead; residual x folded into acc during PV (C-in linearity).
// =====================================================================
#define GT_OFF  32768
#define HS_OFF  131072
#define SMAX_OFF 151552
#define SSUM_OFF 153600
#define SMEM_BYTES 155648

__global__ __launch_bounds__(512, 1) void attn_kernel(
    const bf16_t* __restrict__ mF, const bf16_t* __restrict__ mG, const bf16_t* __restrict__ mH,
    const float* __restrict__ x, float* __restrict__ out, int b0)
{
  extern __shared__ __align__(16) char smem[];
  const int t = threadIdx.x;
  const int c = blockIdx.x, bloc = blockIdx.y;
  const int wv = t >> 6, lane = t & 63, lr = lane & 15, lq = lane >> 4;
  const int wr = wv >> 1, wc = wv & 1;
  const size_t plane  = ((size_t)bloc * C_ + c) * HW_;            // maps (per-pass)
  const size_t gplane = (((size_t)(b0 + bloc)) * C_ + c) * HW_;   // x / out (global)

  const f32x4 fz = {0.f, 0.f, 0.f, 0.f};
  f32x4 acc[4][8];
  #pragma unroll
  for (int mf = 0; mf < 4; ++mf)
    #pragma unroll
    for (int nf = 0; nf < 8; ++nf)
      acc[mf][nf] = fz;

  const int hq = t >> 5, wb8 = t & 31;   // staging decomposition

  // ---- S = F^T G, 4 chunks of 64 h; 2-deep global prefetch ----
  bf16x8 pfF[2][4], pfG[2][4];
  #pragma unroll
  for (int p = 0; p < 2; ++p)
    #pragma unroll
    for (int i = 0; i < 4; ++i) {
      pfF[p][i] = *(const bf16x8*)(mF + plane + (size_t)(p * 64 + hq * 4 + i) * 256 + wb8 * 8);
      pfG[p][i] = *(const bf16x8*)(mG + plane + (size_t)(p * 64 + hq * 4 + i) * 256 + wb8 * 8);
    }

  #pragma unroll
  for (int ci = 0; ci < 4; ++ci) {
    const int buf = ci & 1;
    BAR();                             // prev chunk's LDS reads done; Ft/Gt writable
    #pragma unroll
    for (int j = 0; j < 8; ++j) {      // transpose-write (waits vmcnt on pf[buf] only)
      int w = wb8 * 8 + j;
      bf16x4 v; v[0] = pfF[buf][0][j]; v[1] = pfF[buf][1][j];
      v[2] = pfF[buf][2][j]; v[3] = pfF[buf][3][j];
      *(bf16x4*)(smem + ((w * 128 + hq * 8) ^ swz(w))) = v;
      bf16x4 g; g[0] = pfG[buf][0][j]; g[1] = pfG[buf][1][j];
      g[2] = pfG[buf][2][j]; g[3] = pfG[buf][3][j];
      *(bf16x4*)(smem + GT_OFF + ((w * 128 + hq * 8) ^ swz(w))) = g;
    }
    if (ci < 2) {                      // issue chunk ci+2 into just-freed regs
      #pragma unroll
      for (int i = 0; i < 4; ++i) {
        pfF[buf][i] = *(const bf16x8*)(mF + plane + (size_t)((ci + 2) * 64 + hq * 4 + i) * 256 + wb8 * 8);
        pfG[buf][i] = *(const bf16x8*)(mG + plane + (size_t)((ci + 2) * 64 + hq * 4 + i) * 256 + wb8 * 8);
      }
    }
    LGKM0(); BAR();                    // LDS writes visible; vmcnt NOT drained
    #pragma unroll
    for (int k0 = 0; k0 < 64; k0 += 32) {
      int kb = k0 + lq * 8;
      bf16x8 a[4], bb[8];
      #pragma unroll
      for (int mf = 0; mf < 4; ++mf) {
        int m = wr * 64 + mf * 16 + lr;
        a[mf] = *(const bf16x8*)(smem + ((m * 128 + kb * 2) ^ swz(m)));
      }
      #pragma unroll
      for (int nf = 0; nf < 8; ++nf) {
        int n = wc * 128 + nf * 16 + lr;
        bb[nf] = *(const bf16x8*)(smem + GT_OFF + ((n * 128 + kb * 2) ^ swz(n)));
      }
      #pragma unroll
      for (int mf = 0; mf < 4; ++mf)
        #pragma unroll
        for (int nf = 0; nf < 8; ++nf)
          acc[mf][nf] = __builtin_amdgcn_mfma_f32_16x16x32_bf16(a[mf], bb[nf], acc[mf][nf], 0, 0, 0);
    }
  }

  // ---- softmax over v (rows w) (R1 verbatim) ----
  float* smax = (float*)(smem + SMAX_OFF);
  float* ssum = (float*)(smem + SSUM_OFF);
  float rowm[4][4];
  #pragma unroll
  for (int mf = 0; mf < 4; ++mf)
    #pragma unroll
    for (int i = 0; i < 4; ++i) {
      float m = acc[mf][0][i];
      #pragma unroll
      for (int nf = 1; nf < 8; ++nf) m = fmaxf(m, acc[mf][nf][i]);
      #pragma unroll
      for (int d = 1; d < 16; d <<= 1) m = fmaxf(m, __shfl_xor(m, d));
      rowm[mf][i] = m;
    }
  if (lr == 0) {
    #pragma unroll
    for (int mf = 0; mf < 4; ++mf)
      #pragma unroll
      for (int i = 0; i < 4; ++i)
        smax[wc * 256 + wr * 64 + mf * 16 + lq * 4 + i] = rowm[mf][i];
  }
  __syncthreads();
  float m2[4][4], rs[4][4];
  #pragma unroll
  for (int mf = 0; mf < 4; ++mf)
    #pragma unroll
    for (int i = 0; i < 4; ++i) {
      int w = wr * 64 + mf * 16 + lq * 4 + i;
      m2[mf][i] = fmaxf(smax[w], smax[256 + w]);
      rs[mf][i] = 0.f;
    }
  #pragma unroll
  for (int mf = 0; mf < 4; ++mf)
    #pragma unroll
    for (int nf = 0; nf < 8; ++nf)
      #pragma unroll
      for (int i = 0; i < 4; ++i) {
        float e = __expf(acc[mf][nf][i] - m2[mf][i]);
        acc[mf][nf][i] = e;
        rs[mf][i] += e;
      }
  #pragma unroll
  for (int mf = 0; mf < 4; ++mf)
    #pragma unroll
    for (int i = 0; i < 4; ++i) {
      float s = rs[mf][i];
      #pragma unroll
      for (int d = 1; d < 16; d <<= 1) s += __shfl_xor(s, d);
      rs[mf][i] = s;
    }
  if (lr == 0) {
    #pragma unroll
    for (int mf = 0; mf < 4; ++mf)
      #pragma unroll
      for (int i = 0; i < 4; ++i)
        ssum[wc * 256 + wr * 64 + mf * 16 + lq * 4 + i] = rs[mf][i];
  }
  __syncthreads();
  // P = e/sum -> bf16 -> PT[v][w]  (overwrites Ft/Gt region; ordered by barriers)
  #pragma unroll
  for (int mf = 0; mf < 4; ++mf)
    #pragma unroll
    for (int i = 0; i < 4; ++i) {
      int w = wr * 64 + mf * 16 + lq * 4 + i;
      float rinv = 1.f / (ssum[w] + ssum[256 + w]);
      #pragma unroll
      for (int nf = 0; nf < 8; ++nf) {
        int v_ = wc * 128 + nf * 16 + lr;
        *(bf16_t*)(smem + ((v_ * 512 + w * 2) ^ swz(v_))) = (bf16_t)(acc[mf][nf][i] * rinv);
      }
    }

  // ---- out = H*P + x: 8 w-chunks; H 1-ahead; x batches overlap PV ----
  #pragma unroll
  for (int mf = 0; mf < 4; ++mf)
    #pragma unroll
    for (int nf = 0; nf < 8; ++nf)
      acc[mf][nf] = fz;

  // issue chunk-0 H loads early (latency hides under P-write + first barrier)
  bf16x8 hreg[2];
  {
    #pragma unroll
    for (int rep = 0; rep < 2; ++rep) {
      int u = rep * 512 + t;
      int h = u >> 2, wl0 = (u & 3) * 8;
      hreg[rep] = *(const bf16x8*)(mH + plane + h * 64 + wl0);
    }
  }
  // issue x batch 0 (tile mf=0, nf 0..3) AFTER H0 so H0's wait leaves x in flight
  float xv[16];
  #pragma unroll
  for (int n0 = 0; n0 < 4; ++n0)
    #pragma unroll
    for (int i = 0; i < 4; ++i)
      xv[n0 * 4 + i] = x[gplane + (size_t)(wr * 64 + lq * 4 + i) * 256
                         + wc * 128 + n0 * 16 + lr];

  #pragma unroll
  for (int wk = 0; wk < 8; ++wk) {
    LGKM0(); BAR();                    // P-write / prev MFMA reads done; Hs writable
    {
      #pragma unroll
      for (int rep = 0; rep < 2; ++rep) {
        int u = rep * 512 + t;
        int h = u >> 2, wl0 = (u & 3) * 8;
        *(bf16x8*)(smem + HS_OFF + h * 80 + wl0 * 2) = hreg[rep];  // waits vmcnt on hreg
      }
    }
    if (wk < 7) {                      // issue next H chunk; stays in flight across BAR
      const size_t hbase = plane + (size_t)((wk + 1) >> 1) * 16384 + (size_t)((wk + 1) & 1) * 32;
      #pragma unroll
      for (int rep = 0; rep < 2; ++rep) {
        int u = rep * 512 + t;
        int h = u >> 2, wl0 = (u & 3) * 8;
        hreg[rep] = *(const bf16x8*)(mH + hbase + h * 64 + wl0);
      }
    }
    LGKM0(); BAR();                    // Hs writes visible; vmcnt NOT drained
    const int kb = lq * 8;
    bf16x8 a[4], bb[8];
    #pragma unroll
    for (int mf = 0; mf < 4; ++mf) {
      int m = wr * 64 + mf * 16 + lr;
      a[mf] = *(const bf16x8*)(smem + HS_OFF + m * 80 + kb * 2);
    }
    #pragma unroll
    for (int nf = 0; nf < 8; ++nf) {
      int n = wc * 128 + nf * 16 + lr;
      int kg = wk * 32 + kb;
      bb[nf] = *(const bf16x8*)(smem + ((n * 512 + kg * 2) ^ swz(n)));
    }
    #pragma unroll
    for (int mf = 0; mf < 4; ++mf)
      #pragma unroll
      for (int nf = 0; nf < 8; ++nf)
        acc[mf][nf] = __builtin_amdgcn_mfma_f32_16x16x32_bf16(a[mf], bb[nf], acc[mf][nf], 0, 0, 0);

    // fold x batch wk into acc (C-in linearity), then issue batch wk+1
    {
      const int mfb = wk >> 1, nhb = wk & 1;
      #pragma unroll
      for (int n0 = 0; n0 < 4; ++n0)
        #pragma unroll
        for (int i = 0; i < 4; ++i)
          acc[mfb][nhb * 4 + n0][i] += xv[n0 * 4 + i];   // waits vmcnt on xv only
      if (wk < 7) {
        const int mfn = (wk + 1) >> 1, nhn = (wk + 1) & 1;
        #pragma unroll
        for (int n0 = 0; n0 < 4; ++n0)
          #pragma unroll
          for (int i = 0; i < 4; ++i)
            xv[n0 * 4 + i] = x[gplane + (size_t)(wr * 64 + mfn * 16 + lq * 4 + i) * 256
                               + wc * 128 + (nhn * 4 + n0) * 16 + lr];
      }
    }
  }

  // ---- epilogue: pure stores (x already folded in) ----
  #pragma unroll
  for (int mf = 0; mf < 4; ++mf)
    #pragma unroll
    for (int i = 0; i < 4; ++i) {
      int h = wr * 64 + mf * 16 + lq * 4 + i;
      #pragma unroll
      for (int nf = 0; nf < 8; ++nf) {
        int v_ = wc * 128 + nf * 16 + lr;
        out[gplane + (size_t)h * 256 + v_] = acc[mf][nf][i];
      }
    }
}

// =====================================================================
extern "C" void kernel_launch(void* const* d_in, const int* in_sizes, int n_in,
                              void* d_out, int out_size, void* d_ws, size_t ws_size,
                              hipStream_t stream)
{
  (void)in_sizes; (void)n_in; (void)out_size;
  const float* x   = (const float*)d_in[0];
  const float* Wf  = (const float*)d_in[1];
  const float* bfp = (const float*)d_in[2];
  const float* afp = (const float*)d_in[3];
  const float* Wg  = (const float*)d_in[4];
  const float* bgp = (const float*)d_in[5];
  const float* agp = (const float*)d_in[6];
  const float* Wh  = (const float*)d_in[7];
  const float* bhp = (const float*)d_in[8];
  const float* ahp = (const float*)d_in[9];
  float* out = (float*)d_out;

  const size_t per_map_b = (size_t)C_ * HW_ * sizeof(bf16_t);  // 16 MiB per map per batch
  int nb = 1;
  if      (ws_size >= 3 * 8 * per_map_b) nb = 8;
  else if (ws_size >= 3 * 4 * per_map_b) nb = 4;
  else if (ws_size >= 3 * 2 * per_map_b) nb = 2;

  hipFuncSetAttribute(reinterpret_cast<const void*>(attn_kernel),
                      hipFuncAttributeMaxDynamicSharedMemorySize, SMEM_BYTES);

  bf16_t* mF = (bf16_t*)d_ws;
  bf16_t* mG = mF + (size_t)nb * C_ * HW_;
  bf16_t* mH = mG + (size_t)nb * C_ * HW_;

  for (int b0 = 0; b0 < 8; b0 += nb) {
    conv_kernel<<<dim3(512, nb), 256, 0, stream>>>(x, Wf, bfp, afp, Wg, bgp, agp,
                                                   Wh, bhp, ahp, mF, mG, mH, b0);
    attn_kernel<<<dim3(C_, nb), 512, SMEM_BYTES, stream>>>(mF, mG, mH, x, out, b0);
  }
}

// Round 13
// 396.917 us; speedup vs baseline: 1.2361x; 1.2342x over previous
//
#include <hip/hip_runtime.h>

typedef __bf16 bf16_t;
typedef __bf16 bf16x8 __attribute__((ext_vector_type(8)));
typedef __bf16 bf16x4 __attribute__((ext_vector_type(4)));
typedef float  f32x4  __attribute__((ext_vector_type(4)));

#define HW_ 65536
#define C_  128

// XOR swizzle: spread 16B slots (byte bits [6:4]) by row index. Applied
// identically on LDS write and read; bijective within each 128B span.
__device__ __forceinline__ int swz(int r) { return ((r ^ (r >> 3)) & 7) << 4; }

#define LGKM0() asm volatile("s_waitcnt lgkmcnt(0)" ::: "memory")
__device__ __forceinline__ void BAR() {
  asm volatile("" ::: "memory");
  __builtin_amdgcn_s_barrier();
  asm volatile("" ::: "memory");
}

// =====================================================================
// Phase 1 (R1 verbatim, measured 154us): map = PReLU(W*x + b).
// Per-b GEMM M=128,K=128,N=128/WG.
// LDS: Xs at 0 (32KB): x-tile transposed bf16; Ws at 32768 (32KB).
// HBLK: mH w-blocked [c][w>>6][h][w&63] for attn PV staging reads.
// =====================================================================
template<bool HBLK>
__device__ __forceinline__ void conv_one(char* lds, const float* __restrict__ Wsrc,
                                         const float* __restrict__ bias, float alpha,
                                         bf16_t* __restrict__ dst, size_t pb,
                                         int wv, int lr, int lq, int t, int s0)
{
  __syncthreads();
  #pragma unroll
  for (int rep = 0; rep < 16; ++rep) {
    int q = rep * 256 + t;
    int o = q >> 5, c0 = (q & 31) * 4;
    f32x4 w4 = *(const f32x4*)(Wsrc + o * C_ + c0);
    bf16x4 v;
    v[0] = (bf16_t)w4[0]; v[1] = (bf16_t)w4[1]; v[2] = (bf16_t)w4[2]; v[3] = (bf16_t)w4[3];
    *(bf16x4*)(lds + 32768 + ((o * 256 + c0 * 2) ^ swz(o))) = v;
  }
  __syncthreads();

  const f32x4 fz = {0.f, 0.f, 0.f, 0.f};
  f32x4 acc[2][8];
  #pragma unroll
  for (int mf = 0; mf < 2; ++mf)
    #pragma unroll
    for (int nf = 0; nf < 8; ++nf)
      acc[mf][nf] = fz;

  #pragma unroll
  for (int ks = 0; ks < 4; ++ks) {
    int kb = ks * 32 + lq * 8;
    bf16x8 a[2], bb[8];
    #pragma unroll
    for (int mf = 0; mf < 2; ++mf) {
      int m = wv * 32 + mf * 16 + lr;
      a[mf] = *(const bf16x8*)(lds + 32768 + ((m * 256 + kb * 2) ^ swz(m)));
    }
    #pragma unroll
    for (int nf = 0; nf < 8; ++nf) {
      int n = nf * 16 + lr;
      bb[nf] = *(const bf16x8*)(lds + ((n * 256 + kb * 2) ^ swz(n)));
    }
    #pragma unroll
    for (int mf = 0; mf < 2; ++mf)
      #pragma unroll
      for (int nf = 0; nf < 8; ++nf)
        acc[mf][nf] = __builtin_amdgcn_mfma_f32_16x16x32_bf16(a[mf], bb[nf], acc[mf][nf], 0, 0, 0);
  }

  #pragma unroll
  for (int mf = 0; mf < 2; ++mf) {
    #pragma unroll
    for (int i = 0; i < 4; ++i) {
      int o = wv * 32 + mf * 16 + lq * 4 + i;
      float bo = bias[o];
      #pragma unroll
      for (int nf = 0; nf < 8; ++nf) {
        int s = s0 + nf * 16 + lr;
        float v = acc[mf][nf][i] + bo;
        v = (v >= 0.f) ? v : alpha * v;
        size_t off;
        if (HBLK) {                       // w-blocked layout [c][w>>6][h][w&63]
          int h = s >> 8, w = s & 255;
          off = pb + (size_t)o * HW_ + (size_t)(w >> 6) * 16384 + h * 64 + (w & 63);
        } else {
          off = pb + (size_t)o * HW_ + s; // natural [c][h][w]
        }
        dst[off] = (bf16_t)v;
      }
    }
  }
}

__global__ __launch_bounds__(256, 2) void conv_kernel(
    const float* __restrict__ x,
    const float* __restrict__ Wf, const float* __restrict__ bfp, const float* __restrict__ afp,
    const float* __restrict__ Wg, const float* __restrict__ bgp, const float* __restrict__ agp,
    const float* __restrict__ Wh, const float* __restrict__ bhp, const float* __restrict__ ahp,
    bf16_t* __restrict__ mF, bf16_t* __restrict__ mG, bf16_t* __restrict__ mH, int b0)
{
  __shared__ __align__(16) char lds[65536];
  const int t = threadIdx.x;
  const int bloc = blockIdx.y;
  const int s0 = blockIdx.x * 128;
  const size_t xbase = ((size_t)(b0 + bloc) * C_) * HW_ + s0;

  #pragma unroll
  for (int rep = 0; rep < 4; ++rep) {
    int q = rep * 256 + t;
    int c0 = (q >> 5) * 4, sl0 = (q & 31) * 4;
    f32x4 r[4];
    #pragma unroll
    for (int i = 0; i < 4; ++i)
      r[i] = *(const f32x4*)(x + xbase + (size_t)(c0 + i) * HW_ + sl0);
    #pragma unroll
    for (int js = 0; js < 4; ++js) {
      int s = sl0 + js;
      bf16x4 v;
      v[0] = (bf16_t)r[0][js]; v[1] = (bf16_t)r[1][js];
      v[2] = (bf16_t)r[2][js]; v[3] = (bf16_t)r[3][js];
      *(bf16x4*)(lds + ((s * 256 + c0 * 2) ^ swz(s))) = v;
    }
  }

  const int wv = t >> 6, lane = t & 63, lr = lane & 15, lq = lane >> 4;
  const size_t pb = (size_t)bloc * C_ * HW_;
  conv_one<false>(lds, Wf, bfp, afp[0], mF, pb, wv, lr, lq, t, s0);
  conv_one<false>(lds, Wg, bgp, agp[0], mG, pb, wv, lr, lq, t, s0);
  conv_one<true >(lds, Wh, bhp, ahp[0], mH, pb, wv, lr, lq, t, s0);
}

// =====================================================================
// Phase 2 (R10 + PV x-fold only): 512 thr / 8 waves.
// Unified-RF budget at 2 waves/SIMD is 256 regs/thread total; S-acc (128
// AGPR) + S-phase staging fills it -> NO new S-phase state (R11 lesson).
// xv[16] is PV-phase-only liveness and fits below the S-phase peak.
// LDS map (155648 B):
//   [0,32768)        Ft chunk  [w=256][h=64] bf16 swizzled   (S phase)
//   [32768,65536)    Gt chunk  [v=256][h=64] bf16 swizzled   (S phase)
//   [0,131072)       PT        [v=256][w=256] bf16 swizzled  (PV phase)
//   [131072,151552)  Hs chunk  [h=256][w=32] bf16, 80B row pitch
//   [151552,153600)  smax [2][256] f32 ; [153600,155648) ssum [2][256] f32
// S: depth-1 global prefetch across raw barriers (R10, verified +gain).
// PV: H 1-ahead (R9); x folded into acc during PV -> epilogue pure stores.
// =====================================================================
#define GT_OFF  32768
#define HS_OFF  131072
#define SMAX_OFF 151552
#define SSUM_OFF 153600
#define SMEM_BYTES 155648

__global__ __launch_bounds__(512, 2) void attn_kernel(
    const bf16_t* __restrict__ mF, const bf16_t* __restrict__ mG, const bf16_t* __restrict__ mH,
    const float* __restrict__ x, float* __restrict__ out, int b0)
{
  extern __shared__ __align__(16) char smem[];
  const int t = threadIdx.x;
  const int c = blockIdx.x, bloc = blockIdx.y;
  const int wv = t >> 6, lane = t & 63, lr = lane & 15, lq = lane >> 4;
  const int wr = wv >> 1, wc = wv & 1;
  const size_t plane  = ((size_t)bloc * C_ + c) * HW_;            // maps (per-pass)
  const size_t gplane = (((size_t)(b0 + bloc)) * C_ + c) * HW_;   // x / out (global)

  const f32x4 fz = {0.f, 0.f, 0.f, 0.f};
  f32x4 acc[4][8];
  #pragma unroll
  for (int mf = 0; mf < 4; ++mf)
    #pragma unroll
    for (int nf = 0; nf < 8; ++nf)
      acc[mf][nf] = fz;

  const int hq = t >> 5, wb8 = t & 31;   // staging decomposition

  // ---- S = F^T G, K(=h) chunks of 64; depth-1 prefetch across barriers ----
  bf16x8 pfF[4], pfG[4];
  #pragma unroll
  for (int i = 0; i < 4; ++i) {
    pfF[i] = *(const bf16x8*)(mF + plane + (size_t)(hq * 4 + i) * 256 + wb8 * 8);
    pfG[i] = *(const bf16x8*)(mG + plane + (size_t)(hq * 4 + i) * 256 + wb8 * 8);
  }

  for (int hb = 0; hb < 256; hb += 64) {
    BAR();                             // prev chunk's LDS reads done; Ft/Gt writable
    #pragma unroll
    for (int j = 0; j < 8; ++j) {      // transpose-write (waits vmcnt on pf regs)
      int w = wb8 * 8 + j;
      bf16x4 v; v[0] = pfF[0][j]; v[1] = pfF[1][j]; v[2] = pfF[2][j]; v[3] = pfF[3][j];
      *(bf16x4*)(smem + ((w * 128 + hq * 8) ^ swz(w))) = v;
      bf16x4 g; g[0] = pfG[0][j]; g[1] = pfG[1][j]; g[2] = pfG[2][j]; g[3] = pfG[3][j];
      *(bf16x4*)(smem + GT_OFF + ((w * 128 + hq * 8) ^ swz(w))) = g;
    }
    if (hb < 192) {                    // issue next chunk; flies across BAR + MFMAs
      #pragma unroll
      for (int i = 0; i < 4; ++i) {
        pfF[i] = *(const bf16x8*)(mF + plane + (size_t)(hb + 64 + hq * 4 + i) * 256 + wb8 * 8);
        pfG[i] = *(const bf16x8*)(mG + plane + (size_t)(hb + 64 + hq * 4 + i) * 256 + wb8 * 8);
      }
    }
    LGKM0(); BAR();                    // LDS writes visible; vmcnt NOT drained
    #pragma unroll
    for (int k0 = 0; k0 < 64; k0 += 32) {
      int kb = k0 + lq * 8;
      bf16x8 a[4], bb[8];
      #pragma unroll
      for (int mf = 0; mf < 4; ++mf) {
        int m = wr * 64 + mf * 16 + lr;
        a[mf] = *(const bf16x8*)(smem + ((m * 128 + kb * 2) ^ swz(m)));
      }
      #pragma unroll
      for (int nf = 0; nf < 8; ++nf) {
        int n = wc * 128 + nf * 16 + lr;
        bb[nf] = *(const bf16x8*)(smem + GT_OFF + ((n * 128 + kb * 2) ^ swz(n)));
      }
      #pragma unroll
      for (int mf = 0; mf < 4; ++mf)
        #pragma unroll
        for (int nf = 0; nf < 8; ++nf)
          acc[mf][nf] = __builtin_amdgcn_mfma_f32_16x16x32_bf16(a[mf], bb[nf], acc[mf][nf], 0, 0, 0);
    }
  }

  // ---- softmax over v (rows w) (R1 verbatim) ----
  float* smax = (float*)(smem + SMAX_OFF);
  float* ssum = (float*)(smem + SSUM_OFF);
  float rowm[4][4];
  #pragma unroll
  for (int mf = 0; mf < 4; ++mf)
    #pragma unroll
    for (int i = 0; i < 4; ++i) {
      float m = acc[mf][0][i];
      #pragma unroll
      for (int nf = 1; nf < 8; ++nf) m = fmaxf(m, acc[mf][nf][i]);
      #pragma unroll
      for (int d = 1; d < 16; d <<= 1) m = fmaxf(m, __shfl_xor(m, d));
      rowm[mf][i] = m;
    }
  if (lr == 0) {
    #pragma unroll
    for (int mf = 0; mf < 4; ++mf)
      #pragma unroll
      for (int i = 0; i < 4; ++i)
        smax[wc * 256 + wr * 64 + mf * 16 + lq * 4 + i] = rowm[mf][i];
  }
  __syncthreads();
  float m2[4][4], rs[4][4];
  #pragma unroll
  for (int mf = 0; mf < 4; ++mf)
    #pragma unroll
    for (int i = 0; i < 4; ++i) {
      int w = wr * 64 + mf * 16 + lq * 4 + i;
      m2[mf][i] = fmaxf(smax[w], smax[256 + w]);
      rs[mf][i] = 0.f;
    }
  #pragma unroll
  for (int mf = 0; mf < 4; ++mf)
    #pragma unroll
    for (int nf = 0; nf < 8; ++nf)
      #pragma unroll
      for (int i = 0; i < 4; ++i) {
        float e = __expf(acc[mf][nf][i] - m2[mf][i]);
        acc[mf][nf][i] = e;
        rs[mf][i] += e;
      }
  #pragma unroll
  for (int mf = 0; mf < 4; ++mf)
    #pragma unroll
    for (int i = 0; i < 4; ++i) {
      float s = rs[mf][i];
      #pragma unroll
      for (int d = 1; d < 16; d <<= 1) s += __shfl_xor(s, d);
      rs[mf][i] = s;
    }
  if (lr == 0) {
    #pragma unroll
    for (int mf = 0; mf < 4; ++mf)
      #pragma unroll
      for (int i = 0; i < 4; ++i)
        ssum[wc * 256 + wr * 64 + mf * 16 + lq * 4 + i] = rs[mf][i];
  }
  __syncthreads();
  // P = e/sum -> bf16 -> PT[v][w]  (overwrites Ft/Gt region; ordered by barriers)
  #pragma unroll
  for (int mf = 0; mf < 4; ++mf)
    #pragma unroll
    for (int i = 0; i < 4; ++i) {
      int w = wr * 64 + mf * 16 + lq * 4 + i;
      float rinv = 1.f / (ssum[w] + ssum[256 + w]);
      #pragma unroll
      for (int nf = 0; nf < 8; ++nf) {
        int v_ = wc * 128 + nf * 16 + lr;
        *(bf16_t*)(smem + ((v_ * 512 + w * 2) ^ swz(v_))) = (bf16_t)(acc[mf][nf][i] * rinv);
      }
    }

  // ---- out = H*P + x: 8 w-chunks; H 1-ahead; x folded during PV ----
  #pragma unroll
  for (int mf = 0; mf < 4; ++mf)
    #pragma unroll
    for (int nf = 0; nf < 8; ++nf)
      acc[mf][nf] = fz;

  // issue chunk-0 H loads early (latency hides under P-write + first barrier)
  bf16x8 hreg[2];
  {
    #pragma unroll
    for (int rep = 0; rep < 2; ++rep) {
      int u = rep * 512 + t;
      int h = u >> 2, wl0 = (u & 3) * 8;
      hreg[rep] = *(const bf16x8*)(mH + plane + h * 64 + wl0);
    }
  }
  // issue x batch 0 AFTER H0, so H0's wait leaves xv in flight
  float xv[16];
  #pragma unroll
  for (int n0 = 0; n0 < 4; ++n0)
    #pragma unroll
    for (int i = 0; i < 4; ++i)
      xv[n0 * 4 + i] = x[gplane + (size_t)(wr * 64 + lq * 4 + i) * 256
                         + wc * 128 + n0 * 16 + lr];

  for (int wk = 0; wk < 8; ++wk) {
    LGKM0(); BAR();                    // P-write / prev MFMA reads done; Hs writable
    {
      #pragma unroll
      for (int rep = 0; rep < 2; ++rep) {
        int u = rep * 512 + t;
        int h = u >> 2, wl0 = (u & 3) * 8;
        *(bf16x8*)(smem + HS_OFF + h * 80 + wl0 * 2) = hreg[rep];  // waits vmcnt on hreg
      }
    }
    if (wk < 7) {                      // issue next H chunk; stays in flight across BAR
      const size_t hbase = plane + (size_t)((wk + 1) >> 1) * 16384 + (size_t)((wk + 1) & 1) * 32;
      #pragma unroll
      for (int rep = 0; rep < 2; ++rep) {
        int u = rep * 512 + t;
        int h = u >> 2, wl0 = (u & 3) * 8;
        hreg[rep] = *(const bf16x8*)(mH + hbase + h * 64 + wl0);
      }
    }
    LGKM0(); BAR();                    // Hs writes visible; vmcnt NOT drained
    const int kb = lq * 8;
    bf16x8 a[4], bb[8];
    #pragma unroll
    for (int mf = 0; mf < 4; ++mf) {
      int m = wr * 64 + mf * 16 + lr;
      a[mf] = *(const bf16x8*)(smem + HS_OFF + m * 80 + kb * 2);
    }
    #pragma unroll
    for (int nf = 0; nf < 8; ++nf) {
      int n = wc * 128 + nf * 16 + lr;
      int kg = wk * 32 + kb;
      bb[nf] = *(const bf16x8*)(smem + ((n * 512 + kg * 2) ^ swz(n)));
    }
    #pragma unroll
    for (int mf = 0; mf < 4; ++mf)
      #pragma unroll
      for (int nf = 0; nf < 8; ++nf)
        acc[mf][nf] = __builtin_amdgcn_mfma_f32_16x16x32_bf16(a[mf], bb[nf], acc[mf][nf], 0, 0, 0);

    // fold x batch wk into acc (C-in linearity), then issue batch wk+1
    {
      const int mfb = wk >> 1, nhb = wk & 1;
      #pragma unroll
      for (int n0 = 0; n0 < 4; ++n0)
        #pragma unroll
        for (int i = 0; i < 4; ++i)
          acc[mfb][nhb * 4 + n0][i] += xv[n0 * 4 + i];   // waits vmcnt on xv only
      if (wk < 7) {
        const int mfn = (wk + 1) >> 1, nhn = (wk + 1) & 1;
        #pragma unroll
        for (int n0 = 0; n0 < 4; ++n0)
          #pragma unroll
          for (int i = 0; i < 4; ++i)
            xv[n0 * 4 + i] = x[gplane + (size_t)(wr * 64 + mfn * 16 + lq * 4 + i) * 256
                               + wc * 128 + (nhn * 4 + n0) * 16 + lr];
      }
    }
  }

  // ---- epilogue: pure stores (x already folded in) ----
  #pragma unroll
  for (int mf = 0; mf < 4; ++mf)
    #pragma unroll
    for (int i = 0; i < 4; ++i) {
      int h = wr * 64 + mf * 16 + lq * 4 + i;
      #pragma unroll
      for (int nf = 0; nf < 8; ++nf) {
        int v_ = wc * 128 + nf * 16 + lr;
        out[gplane + (size_t)h * 256 + v_] = acc[mf][nf][i];
      }
    }
}

// =====================================================================
extern "C" void kernel_launch(void* const* d_in, const int* in_sizes, int n_in,
                              void* d_out, int out_size, void* d_ws, size_t ws_size,
                              hipStream_t stream)
{
  (void)in_sizes; (void)n_in; (void)out_size;
  const float* x   = (const float*)d_in[0];
  const float* Wf  = (const float*)d_in[1];
  const float* bfp = (const float*)d_in[2];
  const float* afp = (const float*)d_in[3];
  const float* Wg  = (const float*)d_in[4];
  const float* bgp = (const float*)d_in[5];
  const float* agp = (const float*)d_in[6];
  const float* Wh  = (const float*)d_in[7];
  const float* bhp = (const float*)d_in[8];
  const float* ahp = (const float*)d_in[9];
  float* out = (float*)d_out;

  const size_t per_map_b = (size_t)C_ * HW_ * sizeof(bf16_t);  // 16 MiB per map per batch
  int nb = 1;
  if      (ws_size >= 3 * 8 * per_map_b) nb = 8;
  else if (ws_size >= 3 * 4 * per_map_b) nb = 4;
  else if (ws_size >= 3 * 2 * per_map_b) nb = 2;

  hipFuncSetAttribute(reinterpret_cast<const void*>(attn_kernel),
                      hipFuncAttributeMaxDynamicSharedMemorySize, SMEM_BYTES);

  bf16_t* mF = (bf16_t*)d_ws;
  bf16_t* mG = mF + (size_t)nb * C_ * HW_;
  bf16_t* mH = mG + (size_t)nb * C_ * HW_;

  for (int b0 = 0; b0 < 8; b0 += nb) {
    conv_kernel<<<dim3(512, nb), 256, 0, stream>>>(x, Wf, bfp, afp, Wg, bgp, agp,
                                                   Wh, bhp, ahp, mF, mG, mH, b0);
    attn_kernel<<<dim3(C_, nb), 512, SMEM_BYTES, stream>>>(mF, mG, mH, x, out, b0);
  }
}